// Round 4
// baseline (342.853 us; speedup 1.0000x reference)
//
#include <hip/hip_runtime.h>
#include <stdint.h>

typedef unsigned short ushort_t;
typedef __attribute__((ext_vector_type(8))) short short8;
typedef __attribute__((ext_vector_type(4))) float floatx4;

#define B_   8192
#define IN_  1024
#define H_   1024

#define WB_ELEMS   (H_ * IN_)            // 1048576
// ws layout (ushort elements): Wb[8][1M]  (slots: i,f,g,o x-wts then i,f,g,o h-wts)

__device__ __forceinline__ ushort_t f2bf(float f) {
    union { float f; uint32_t i; } v; v.f = f;
    uint32_t r = (v.i + 0x7fffu + ((v.i >> 16) & 1u)) >> 16;
    return (ushort_t)r;
}
__device__ __forceinline__ float sigmoid_(float x) {
    return 1.0f / (1.0f + __expf(-x));
}
__device__ __forceinline__ float tanh_(float x) {
    float xc = fminf(fmaxf(x, -20.f), 20.f);
    float e = __expf(2.f * xc);
    return (e - 1.f) / (e + 1.f);
}

// async global->LDS DMA, 16B/lane; dest must be wave-uniform base + lane*16.
__device__ __forceinline__ void gll16(const ushort_t* gsrc, ushort_t* ldst) {
    __builtin_amdgcn_global_load_lds(
        (const __attribute__((address_space(1))) void*)gsrc,
        (__attribute__((address_space(3))) void*)ldst,
        16, 0, 0);
}

// ---- prep: f32 -> bf16 for the 8 weight matrices only (x/h cvt is fused
// into the GEMM's A staging). 48 MB traffic vs 157 MB in round 2. ----
__global__ __launch_bounds__(256) void cvt_kernel(
    const float* __restrict__ Wix, const float* __restrict__ Wfx,
    const float* __restrict__ Wgx, const float* __restrict__ Wox,
    const float* __restrict__ Wih, const float* __restrict__ Wfh,
    const float* __restrict__ Wgh, const float* __restrict__ Woh,
    ushort_t* __restrict__ ws)
{
    const int c = blockIdx.x * 256 + threadIdx.x;   // 0..1048575
    const int s = c >> 17;                          // weight slot 0..7
    const float* w =
        s == 0 ? Wix : s == 1 ? Wfx : s == 2 ? Wgx : s == 3 ? Wox :
        s == 4 ? Wih : s == 5 ? Wfh : s == 6 ? Wgh : Woh;
    const int off = (c & 131071) * 8;
    ushort_t* dst = ws + s * WB_ELEMS;
    float4 f0 = *(const float4*)(w + off);
    float4 f1 = *(const float4*)(w + off + 4);
    short8 o;
    o[0] = (short)f2bf(f0.x); o[1] = (short)f2bf(f0.y);
    o[2] = (short)f2bf(f0.z); o[3] = (short)f2bf(f0.w);
    o[4] = (short)f2bf(f1.x); o[5] = (short)f2bf(f1.y);
    o[6] = (short)f2bf(f1.z); o[7] = (short)f2bf(f1.w);
    *(short8*)(dst + off) = o;
}

// ============================================================================
// 256x256 tile, BK=64, 8 waves (2Mx4N), 4-phase-per-K-tile schedule.
// B (weights): global_load_lds DMA of pre-converted bf16.
// A (x/h):    fused f32->bf16: PLAIN floatx4 loads issued two phases early
//             (compiler-tracked => compiler inserts its own counted vmcnt
//             before the convert; no asm-load regalloc hazard) ->
//             f2bf (RNE bit-trick, bit-identical to cvt_kernel) ->
//             short8 LDS store after the MFMA cluster (T14 split).
//
// Manual waits exist ONLY for the B-DMA -> ds_read ordering (invisible to
// the compiler).  VMEM stream per steady K-tile T:
//   [p0: 4 A-loads][p1: 2 B-gll][p2: 4 A-loads][p3: 2 B-gll]
// WAIT_VM(6) at p0/p2 (before the cvt) keeps newest 6 = {prev 2 B-gll,
// this phase's 4 A-loads}: drains the cvt's A-loads AND guarantees every
// B-gll lands one full phase before its first ds_read.  All reordering
// windows are bounded by "memory"-clobber asm, so no VMEM op crosses a
// wait and each wait's drain-SET is motion-invariant.  Prologue closes
// with a full WAIT_VM(0) (permutation-robust).  Never drains to 0 in the
// steady loop.
//
// Region schedule (slot s = T&1), all writes >=2 barriers after last read:
//   p0: MFMA kh0 rf0-3 | write A(T+1,kh1)->s^1 | issue A-loads (T+2,kh0)
//   p1: MFMA kh0 rf4-7 | DMA  B(T+1,kh1)->s^1
//   p2: MFMA kh1 rf0-3 | write A(T+2,kh0)->s   | issue A-loads (T+2,kh1)
//   p3: MFMA kh1 rf4-7 | DMA  B(T+2,kh0)->s
//
// LDS layout/swizzle identical to round 2 (source-permuted chunks,
// conflict-free frag reads, SQ_LDS_BANK_CONFLICT == 0).
// K order: X k0..1023 (tiles 0-15) then H (16-31) — numerics identical to
// the round-2 baseline (absmax 0.015625).
// ============================================================================

#define BAR()  __builtin_amdgcn_s_barrier()
#define WAIT_VM(N) do{ asm volatile("s_waitcnt vmcnt(" #N ")" ::: "memory"); \
                       __builtin_amdgcn_sched_barrier(0); }while(0)
#define LGKM0() asm volatile("s_waitcnt lgkmcnt(0)" ::: "memory")

// issue 4 plain global f32x4 loads for A half (T2, KH):
// R0,R1 = row r0 chunk c0 (k0-3, k4-7); R2,R3 = row r0+128 same chunk.
#define ISSUE_A(R0, R1, R2, R3, T2, KH) do{ \
    const float* _a0 = (((T2) < 16) ? Xf : Hf) + (((T2) & 15) * 64 + (KH) * 32) + aIdx0; \
    R0 = *(const floatx4*)(_a0); \
    R1 = *(const floatx4*)(_a0 + 4); \
    R2 = *(const floatx4*)(_a0 + 131072); \
    R3 = *(const floatx4*)(_a0 + 131076); \
}while(0)

// cvt 16 f32 -> 16 bf16 (RNE), write two 16B chunks (idx t, t+512) of (DS,KH)
#define CVT_WRITE(R0, R1, R2, R3, DS, KH) do{ \
    short8 _o0, _o1; \
    _o0[0]=(short)f2bf(R0.x); _o0[1]=(short)f2bf(R0.y); \
    _o0[2]=(short)f2bf(R0.z); _o0[3]=(short)f2bf(R0.w); \
    _o0[4]=(short)f2bf(R1.x); _o0[5]=(short)f2bf(R1.y); \
    _o0[6]=(short)f2bf(R1.z); _o0[7]=(short)f2bf(R1.w); \
    _o1[0]=(short)f2bf(R2.x); _o1[1]=(short)f2bf(R2.y); \
    _o1[2]=(short)f2bf(R2.z); _o1[3]=(short)f2bf(R2.w); \
    _o1[4]=(short)f2bf(R3.x); _o1[5]=(short)f2bf(R3.y); \
    _o1[6]=(short)f2bf(R3.z); _o1[7]=(short)f2bf(R3.w); \
    *(short8*)(lds + (DS)*32768 + (KH)*8192 + t*8)        = _o0; \
    *(short8*)(lds + (DS)*32768 + (KH)*8192 + 4096 + t*8) = _o1; \
}while(0)

#define STAGE_B(TS, KH, DS) do{ \
    const ushort_t* _s = Wb + ((((TS) < 16) ? 0 : 4 * WB_ELEMS) + (((TS) & 15) * 64 + (KH) * 32)); \
    ushort_t* _d = lds + ((DS) * 32768 + 16384 + (KH) * 8192); \
    gll16(_s + boff0,         _d + t * 8); \
    gll16(_s + boff0 + 32768, _d + 4096 + t * 8); \
  }while(0)

#define RD_A(S, KH, RF) (*(const short8*)(lds + ((S) * 32768 + (KH) * 8192) + a_rd + (RF) * 512))
#define RD_B(S, KH, CT) (*(const short8*)(lds + ((S) * 32768 + 16384 + (KH) * 8192) + b_rd + (CT) * 512))

#define MFMA16(RFB) do{ \
    __builtin_amdgcn_s_setprio(1); \
    _Pragma("unroll") \
    for (int _rf = 0; _rf < 4; ++_rf) \
      _Pragma("unroll") \
      for (int _ct = 0; _ct < 4; ++_ct) \
        acc[(RFB) + _rf][_ct] = __builtin_amdgcn_mfma_f32_16x16x32_bf16( \
            af[_rf], bfr[_ct], acc[(RFB) + _rf][_ct], 0, 0, 0); \
    __builtin_amdgcn_s_setprio(0); \
  }while(0)

#define KTILE_STEADY(T, S) do{ \
    /* p0: rf0-3 x kh0 */ \
    af[0]=RD_A(S,0,0); bfr[0]=RD_B(S,0,0); af[1]=RD_A(S,0,1); bfr[1]=RD_B(S,0,1); \
    af[2]=RD_A(S,0,2); bfr[2]=RD_B(S,0,2); af[3]=RD_A(S,0,3); bfr[3]=RD_B(S,0,3); \
    ISSUE_A(a00,a01,a02,a03, (T)+2, 0); \
    BAR(); MFMA16(0); \
    WAIT_VM(6); \
    CVT_WRITE(a10,a11,a12,a13, (S)^1, 1);   /* A(T+1,kh1) */ \
    LGKM0(); BAR(); \
    /* p1: rf4-7 x kh0 */ \
    af[0]=RD_A(S,0,4); af[1]=RD_A(S,0,5); af[2]=RD_A(S,0,6); af[3]=RD_A(S,0,7); \
    STAGE_B((T)+1, 1, (S)^1); \
    BAR(); MFMA16(4); BAR(); \
    /* p2: rf0-3 x kh1 */ \
    af[0]=RD_A(S,1,0); bfr[0]=RD_B(S,1,0); af[1]=RD_A(S,1,1); bfr[1]=RD_B(S,1,1); \
    af[2]=RD_A(S,1,2); bfr[2]=RD_B(S,1,2); af[3]=RD_A(S,1,3); bfr[3]=RD_B(S,1,3); \
    ISSUE_A(a10,a11,a12,a13, (T)+2, 1); \
    BAR(); MFMA16(0); \
    WAIT_VM(6); \
    CVT_WRITE(a00,a01,a02,a03, S, 0);       /* A(T+2,kh0) */ \
    LGKM0(); BAR(); \
    /* p3: rf4-7 x kh1 */ \
    af[0]=RD_A(S,1,4); af[1]=RD_A(S,1,5); af[2]=RD_A(S,1,6); af[3]=RD_A(S,1,7); \
    STAGE_B((T)+2, 0, S); \
    BAR(); MFMA16(4); BAR(); \
}while(0)

__global__ __launch_bounds__(512, 2) void lstm_cell_kernel(
    const float* __restrict__ Xf,  const float* __restrict__ Hf,
    const ushort_t* __restrict__ Wb,  // 8 slots of [H][K] bf16
    const float* __restrict__ Cprev,
    const float* __restrict__ Bi, const float* __restrict__ Bf,
    const float* __restrict__ Bg, const float* __restrict__ Bo,
    float* __restrict__ Out)
{
    __shared__ __align__(16) ushort_t lds[65536];   // 128 KiB

    const int t   = threadIdx.x;                    // 0..511
    const int bm0 = blockIdx.y * 256;
    const int j0  = blockIdx.x * 64;

    // ---- staging precompute ----
    // A chunks: thread t owns phys chunk idx t (row r0=t>>2) and t+512
    // (row r0+128); logical k-chunk c0 = (t&3)^((t>>3)&3) (source-permuted
    // swizzle; same c0 for both rows since 512>>3 ≡ 0 mod 4).
    const int r0 = t >> 2;
    const int c0 = (t & 3) ^ ((t >> 3) & 3);
    const int aIdx0 = (bm0 + r0) * 1024 + c0 * 8;           // f32 elements
    // B: virtual row v -> gate (v>>4)&3, j = j0 + (v>>6)*16 + (v&15)
    const int g0  = (r0 >> 4) & 3;
    const int jv0 = j0 + ((r0 >> 6) << 4) + (r0 & 15);
    const int boff0 = g0 * WB_ELEMS + jv0 * 1024 + c0 * 8;  // bf16 elements

    // ---- fragment read addressing ----
    const int lane = t & 63;
    const int wid  = t >> 6;
    const int wr = wid >> 2, wc = wid & 3;          // 2M x 4N waves
    const int lr = lane & 15, lk = lane >> 4;
    const int xk = lk ^ ((lr >> 1) & 3);            // bank swizzle
    const int a_rd = (wr * 512 + lr * 4 + xk) * 8;  // ushort offset in A half
    const int b_rd = (wc * 256 + lr * 4 + xk) * 8;  // ushort offset in B half

    short8 af[4], bfr[4];
    floatx4 a00, a01, a02, a03, a10, a11, a12, a13;  // A-staging regs (named: rule 20)
    floatx4 p10, p11, p12, p13, p20, p21, p22, p23;  // prologue-only temps
    floatx4 acc[8][4] = {};   // [row-frag][gate]

    // ---- prologue: issue A(0,0),A(0,1),A(1,0),A(1,1) + B(0,*),B(1,0);
    // full drain (robust to any VMEM issue-order permutation in this
    // single clobber-free window), convert/write the first three A-halves,
    // make them visible. A(1,1) stays in regs a10-a13 for tile 0's p0. ----
    ISSUE_A(a00,a01,a02,a03, 0, 0);
    ISSUE_A(p10,p11,p12,p13, 0, 1);
    ISSUE_A(p20,p21,p22,p23, 1, 0);
    STAGE_B(0, 0, 0); STAGE_B(0, 1, 0);
    ISSUE_A(a10,a11,a12,a13, 1, 1);
    STAGE_B(1, 0, 1);
    WAIT_VM(0);
    CVT_WRITE(a00,a01,a02,a03, 0, 0);   // A(0,0)
    CVT_WRITE(p10,p11,p12,p13, 0, 1);   // A(0,1)
    CVT_WRITE(p20,p21,p22,p23, 1, 0);   // A(1,0)
    LGKM0();
    BAR();

    // ---- main loop: tiles 0..29 steady; tail 30/31 peeled ----
    for (int T = 0; T < 30; T += 2) {
        KTILE_STEADY(T,     0);
        KTILE_STEADY(T + 1, 1);
    }

    // tile 30 (slot 0): stages only A(31,1) + B(31,1); drain at p3
    {
        af[0]=RD_A(0,0,0); bfr[0]=RD_B(0,0,0); af[1]=RD_A(0,0,1); bfr[1]=RD_B(0,0,1);
        af[2]=RD_A(0,0,2); bfr[2]=RD_B(0,0,2); af[3]=RD_A(0,0,3); bfr[3]=RD_B(0,0,3);
        BAR(); MFMA16(0);
        WAIT_VM(2);                       // only B(31,0) gll may stay in flight
        CVT_WRITE(a10,a11,a12,a13, 1, 1); // A(31,1)
        LGKM0(); BAR();
        af[0]=RD_A(0,0,4); af[1]=RD_A(0,0,5); af[2]=RD_A(0,0,6); af[3]=RD_A(0,0,7);
        STAGE_B(31, 1, 1);
        BAR(); MFMA16(4); BAR();
        af[0]=RD_A(0,1,0); bfr[0]=RD_B(0,1,0); af[1]=RD_A(0,1,1); bfr[1]=RD_B(0,1,1);
        af[2]=RD_A(0,1,2); bfr[2]=RD_B(0,1,2); af[3]=RD_A(0,1,3); bfr[3]=RD_B(0,1,3);
        BAR(); MFMA16(0); BAR();
        af[0]=RD_A(0,1,4); af[1]=RD_A(0,1,5); af[2]=RD_A(0,1,6); af[3]=RD_A(0,1,7);
        BAR(); MFMA16(4);
        WAIT_VM(0);                       // B(31,0), B(31,1) landed
        BAR();
    }
    // tile 31 (slot 1): plain compute, no staging
    {
        af[0]=RD_A(1,0,0); bfr[0]=RD_B(1,0,0); af[1]=RD_A(1,0,1); bfr[1]=RD_B(1,0,1);
        af[2]=RD_A(1,0,2); bfr[2]=RD_B(1,0,2); af[3]=RD_A(1,0,3); bfr[3]=RD_B(1,0,3);
        BAR(); MFMA16(0); BAR();
        af[0]=RD_A(1,0,4); af[1]=RD_A(1,0,5); af[2]=RD_A(1,0,6); af[3]=RD_A(1,0,7);
        BAR(); MFMA16(4); BAR();
        af[0]=RD_A(1,1,0); bfr[0]=RD_B(1,1,0); af[1]=RD_A(1,1,1); bfr[1]=RD_B(1,1,1);
        af[2]=RD_A(1,1,2); bfr[2]=RD_B(1,1,2); af[3]=RD_A(1,1,3); bfr[3]=RD_B(1,1,3);
        BAR(); MFMA16(0); BAR();
        af[0]=RD_A(1,1,4); af[1]=RD_A(1,1,5); af[2]=RD_A(1,1,6); af[3]=RD_A(1,1,7);
        BAR(); MFMA16(4); BAR();
    }

    // ---- epilogue: 4 gates live in acc[rf][0..3], same lane/reg ----
    const int j = j0 + wc * 16 + lr;
    const float bi = Bi[j], bff = Bf[j], bg = Bg[j], bo = Bo[j];

    #pragma unroll
    for (int rf = 0; rf < 8; ++rf) {
        #pragma unroll
        for (int reg = 0; reg < 4; ++reg) {
            const int m = bm0 + wr * 128 + rf * 16 + lk * 4 + reg;
            const float zi = acc[rf][0][reg] + bi;
            const float zf = acc[rf][1][reg] + bff;
            const float zg = acc[rf][2][reg] + bg;
            const float zo = acc[rf][3][reg] + bo;
            const float ig = sigmoid_(zi);
            const float fg = sigmoid_(zf);
            const float gg = tanh_(zg);
            const float og = sigmoid_(zo);
            const float cp = Cprev[(size_t)m * H_ + j];
            const float cn = fg * cp + ig * gg;
            const float hn = og * tanh_(cn);
            Out[(size_t)m * H_ + j] = hn;                             // h_next (f32)
            Out[(size_t)B_ * H_ + (size_t)m * H_ + j] = cn;           // c_next (f32)
        }
    }
}

extern "C" void kernel_launch(void* const* d_in, const int* in_sizes, int n_in,
                              void* d_out, int out_size, void* d_ws, size_t ws_size,
                              hipStream_t stream)
{
    (void)in_sizes; (void)n_in; (void)out_size; (void)ws_size;
    const float* X   = (const float*)d_in[0];
    const float* Hin = (const float*)d_in[1];
    const float* Cp  = (const float*)d_in[2];
    const float* Wfx = (const float*)d_in[3];
    const float* Bf  = (const float*)d_in[4];
    const float* Wfh = (const float*)d_in[5];
    const float* Wix = (const float*)d_in[6];
    const float* Bi  = (const float*)d_in[7];
    const float* Wih = (const float*)d_in[8];
    const float* Wgx = (const float*)d_in[9];
    const float* Bg  = (const float*)d_in[10];
    const float* Wgh = (const float*)d_in[11];
    const float* Wox = (const float*)d_in[12];
    const float* Bo  = (const float*)d_in[13];
    const float* Woh = (const float*)d_in[14];
    float* Out = (float*)d_out;
    ushort_t* ws  = (ushort_t*)d_ws;

    // prep: f32 -> bf16 weights only (x/h cvt fused into GEMM A-staging)
    cvt_kernel<<<dim3(4096), dim3(256), 0, stream>>>(
        Wix, Wfx, Wgx, Wox, Wih, Wfh, Wgh, Woh, ws);

    dim3 grid(H_ / 64, B_ / 256);   // 16 x 32 = 512 blocks
    lstm_cell_kernel<<<grid, dim3(512), 0, stream>>>(
        X, Hin, ws, Cp, Bi, Bf, Bg, Bo, Out);
}

// Round 5
// 335.301 us; speedup vs baseline: 1.0225x; 1.0225x over previous
//
#include <hip/hip_runtime.h>
#include <stdint.h>

typedef unsigned short ushort_t;
typedef __attribute__((ext_vector_type(8))) short short8;
typedef __attribute__((ext_vector_type(4))) float floatx4;
typedef __attribute__((ext_vector_type(4))) unsigned int uint4v;

#define B_   8192
#define IN_  1024
#define H_   1024

#define WB_ELEMS   (H_ * IN_)            // 1048576
// ws layout (ushort elements): Wb[8][1M]  (slots: i,f,g,o x-wts then i,f,g,o h-wts)

__device__ __forceinline__ ushort_t f2bf(float f) {
    union { float f; uint32_t i; } v; v.f = f;
    uint32_t r = (v.i + 0x7fffu + ((v.i >> 16) & 1u)) >> 16;
    return (ushort_t)r;
}
__device__ __forceinline__ float sigmoid_(float x) {
    return 1.0f / (1.0f + __expf(-x));
}
__device__ __forceinline__ float tanh_(float x) {
    float xc = fminf(fmaxf(x, -20.f), 20.f);
    float e = __expf(2.f * xc);
    return (e - 1.f) / (e + 1.f);
}

// async global->LDS DMA, 16B/lane; dest must be wave-uniform base + lane*16.
__device__ __forceinline__ void gll16(const ushort_t* gsrc, ushort_t* ldst) {
    __builtin_amdgcn_global_load_lds(
        (const __attribute__((address_space(1))) void*)gsrc,
        (__attribute__((address_space(3))) void*)ldst,
        16, 0, 0);
}

// ---- prep: f32 -> bf16 for the 8 weight matrices only (x/h cvt is fused
// into the GEMM's A staging). 48 MB traffic vs 157 MB in round 2. ----
__global__ __launch_bounds__(256) void cvt_kernel(
    const float* __restrict__ Wix, const float* __restrict__ Wfx,
    const float* __restrict__ Wgx, const float* __restrict__ Wox,
    const float* __restrict__ Wih, const float* __restrict__ Wfh,
    const float* __restrict__ Wgh, const float* __restrict__ Woh,
    ushort_t* __restrict__ ws)
{
    const int c = blockIdx.x * 256 + threadIdx.x;   // 0..1048575
    const int s = c >> 17;                          // weight slot 0..7
    const float* w =
        s == 0 ? Wix : s == 1 ? Wfx : s == 2 ? Wgx : s == 3 ? Wox :
        s == 4 ? Wih : s == 5 ? Wfh : s == 6 ? Wgh : Woh;
    const int off = (c & 131071) * 8;
    ushort_t* dst = ws + s * WB_ELEMS;
    float4 f0 = *(const float4*)(w + off);
    float4 f1 = *(const float4*)(w + off + 4);
    short8 o;
    o[0] = (short)f2bf(f0.x); o[1] = (short)f2bf(f0.y);
    o[2] = (short)f2bf(f0.z); o[3] = (short)f2bf(f0.w);
    o[4] = (short)f2bf(f1.x); o[5] = (short)f2bf(f1.y);
    o[6] = (short)f2bf(f1.z); o[7] = (short)f2bf(f1.w);
    *(short8*)(dst + off) = o;
}

// ============================================================================
// 256x256 tile, BK=64, 8 waves (2Mx4N), 4-phase-per-K-tile schedule.
// B (weights): global_load_lds DMA of pre-converted bf16.
// A (x/h):    fused f32->bf16: PLAIN floatx4 loads issued two phases early
//             (compiler-tracked, inserts its own counted vmcnt before use)
//             -> v_cvt_pk_bf16_f32 (synchronous VALU asm, RNE; 16 inst for
//             32 values vs ~170 for the f2bf bit-trick -- round-4's
//             regression) -> 16B LDS store after the MFMA cluster.
//
// ROUND-5 CHANGES vs round 4:
//  * CVT via v_cvt_pk_bf16_f32 (non-volatile asm: schedulable, CSE-able).
//    Synchronous op => none of round-3's async-asm-load regalloc hazard.
//  * WAIT_VM no longer carries sched_barrier(0): that pin forced
//    MFMA -> convert -> barrier to serialize (rule #18 applies only to
//    inline-asm ds_reads, which we don't use).  Compiler may now
//    interleave convert VALU + ds_writes into the MFMA shadow
//    (separate pipes), as it did in round 2.
//
// Manual waits exist ONLY for the B-DMA -> ds_read ordering (invisible to
// the compiler).  VMEM stream per steady K-tile T:
//   [p0: 4 A-loads][p1: 2 B-gll][p2: 4 A-loads][p3: 2 B-gll]
// WAIT_VM(6) at p0/p2 keeps newest 6 = {prev 2 B-gll, this phase's 4
// A-loads}: guarantees every B-gll lands >=1 full phase before its first
// ds_read.  FIFO keep-count invariants verified robust under any legal
// instruction motion between the "memory"-clobber waits (incl. STAGE_B /
// A-load migration within a phase window).  Prologue closes with a full
// WAIT_VM(0) (permutation-robust).  Never drains to 0 in the steady loop.
//
// Region schedule (slot s = T&1), all writes >=2 barriers after last read:
//   p0: MFMA kh0 rf0-3 | write A(T+1,kh1)->s^1 | issue A-loads (T+2,kh0)
//   p1: MFMA kh0 rf4-7 | DMA  B(T+1,kh1)->s^1
//   p2: MFMA kh1 rf0-3 | write A(T+2,kh0)->s   | issue A-loads (T+2,kh1)
//   p3: MFMA kh1 rf4-7 | DMA  B(T+2,kh0)->s
//
// LDS layout/swizzle identical to round 2 (source-permuted chunks,
// conflict-free frag reads, SQ_LDS_BANK_CONFLICT == 0).
// K order: X k0..1023 (tiles 0-15) then H (16-31).  v_cvt_pk_bf16_f32 is
// RNE — bit-identical to f2bf for the non-NaN inputs here.
// ============================================================================

#define BAR()  __builtin_amdgcn_s_barrier()
#define WAIT_VM(N) asm volatile("s_waitcnt vmcnt(" #N ")" ::: "memory")
#define LGKM0() asm volatile("s_waitcnt lgkmcnt(0)" ::: "memory")
// synchronous VALU convert: no async-write hazard, freely schedulable
#define CVTPK(U, LO, HI) \
    asm("v_cvt_pk_bf16_f32 %0, %1, %2" : "=v"(U) : "v"(LO), "v"(HI))

// issue 4 plain global f32x4 loads for A half (T2, KH):
// R0,R1 = row r0 chunk c0 (k0-3, k4-7); R2,R3 = row r0+128 same chunk.
#define ISSUE_A(R0, R1, R2, R3, T2, KH) do{ \
    const float* _a0 = (((T2) < 16) ? Xf : Hf) + (((T2) & 15) * 64 + (KH) * 32) + aIdx0; \
    R0 = *(const floatx4*)(_a0); \
    R1 = *(const floatx4*)(_a0 + 4); \
    R2 = *(const floatx4*)(_a0 + 131072); \
    R3 = *(const floatx4*)(_a0 + 131076); \
}while(0)

// cvt 16 f32 -> 16 bf16 (RNE, cvt_pk), write two 16B chunks (idx t, t+512)
#define CVT_WRITE(R0, R1, R2, R3, DS, KH) do{ \
    unsigned int _u0,_u1,_u2,_u3,_u4,_u5,_u6,_u7; \
    CVTPK(_u0, R0.x, R0.y); CVTPK(_u1, R0.z, R0.w); \
    CVTPK(_u2, R1.x, R1.y); CVTPK(_u3, R1.z, R1.w); \
    CVTPK(_u4, R2.x, R2.y); CVTPK(_u5, R2.z, R2.w); \
    CVTPK(_u6, R3.x, R3.y); CVTPK(_u7, R3.z, R3.w); \
    uint4v _w0 = {_u0,_u1,_u2,_u3}; \
    uint4v _w1 = {_u4,_u5,_u6,_u7}; \
    *(uint4v*)(lds + (DS)*32768 + (KH)*8192 + t*8)        = _w0; \
    *(uint4v*)(lds + (DS)*32768 + (KH)*8192 + 4096 + t*8) = _w1; \
}while(0)

#define STAGE_B(TS, KH, DS) do{ \
    const ushort_t* _s = Wb + ((((TS) < 16) ? 0 : 4 * WB_ELEMS) + (((TS) & 15) * 64 + (KH) * 32)); \
    ushort_t* _d = lds + ((DS) * 32768 + 16384 + (KH) * 8192); \
    gll16(_s + boff0,         _d + t * 8); \
    gll16(_s + boff0 + 32768, _d + 4096 + t * 8); \
  }while(0)

#define RD_A(S, KH, RF) (*(const short8*)(lds + ((S) * 32768 + (KH) * 8192) + a_rd + (RF) * 512))
#define RD_B(S, KH, CT) (*(const short8*)(lds + ((S) * 32768 + 16384 + (KH) * 8192) + b_rd + (CT) * 512))

#define MFMA16(RFB) do{ \
    __builtin_amdgcn_s_setprio(1); \
    _Pragma("unroll") \
    for (int _rf = 0; _rf < 4; ++_rf) \
      _Pragma("unroll") \
      for (int _ct = 0; _ct < 4; ++_ct) \
        acc[(RFB) + _rf][_ct] = __builtin_amdgcn_mfma_f32_16x16x32_bf16( \
            af[_rf], bfr[_ct], acc[(RFB) + _rf][_ct], 0, 0, 0); \
    __builtin_amdgcn_s_setprio(0); \
  }while(0)

#define KTILE_STEADY(T, S) do{ \
    /* p0: rf0-3 x kh0 */ \
    af[0]=RD_A(S,0,0); bfr[0]=RD_B(S,0,0); af[1]=RD_A(S,0,1); bfr[1]=RD_B(S,0,1); \
    af[2]=RD_A(S,0,2); bfr[2]=RD_B(S,0,2); af[3]=RD_A(S,0,3); bfr[3]=RD_B(S,0,3); \
    ISSUE_A(a00,a01,a02,a03, (T)+2, 0); \
    BAR(); MFMA16(0); \
    WAIT_VM(6); \
    CVT_WRITE(a10,a11,a12,a13, (S)^1, 1);   /* A(T+1,kh1) */ \
    LGKM0(); BAR(); \
    /* p1: rf4-7 x kh0 */ \
    af[0]=RD_A(S,0,4); af[1]=RD_A(S,0,5); af[2]=RD_A(S,0,6); af[3]=RD_A(S,0,7); \
    STAGE_B((T)+1, 1, (S)^1); \
    BAR(); MFMA16(4); BAR(); \
    /* p2: rf0-3 x kh1 */ \
    af[0]=RD_A(S,1,0); bfr[0]=RD_B(S,1,0); af[1]=RD_A(S,1,1); bfr[1]=RD_B(S,1,1); \
    af[2]=RD_A(S,1,2); bfr[2]=RD_B(S,1,2); af[3]=RD_A(S,1,3); bfr[3]=RD_B(S,1,3); \
    ISSUE_A(a10,a11,a12,a13, (T)+2, 1); \
    BAR(); MFMA16(0); \
    WAIT_VM(6); \
    CVT_WRITE(a00,a01,a02,a03, S, 0);       /* A(T+2,kh0) */ \
    LGKM0(); BAR(); \
    /* p3: rf4-7 x kh1 */ \
    af[0]=RD_A(S,1,4); af[1]=RD_A(S,1,5); af[2]=RD_A(S,1,6); af[3]=RD_A(S,1,7); \
    STAGE_B((T)+2, 0, S); \
    BAR(); MFMA16(4); BAR(); \
}while(0)

__global__ __launch_bounds__(512, 2) void lstm_cell_kernel(
    const float* __restrict__ Xf,  const float* __restrict__ Hf,
    const ushort_t* __restrict__ Wb,  // 8 slots of [H][K] bf16
    const float* __restrict__ Cprev,
    const float* __restrict__ Bi, const float* __restrict__ Bf,
    const float* __restrict__ Bg, const float* __restrict__ Bo,
    float* __restrict__ Out)
{
    __shared__ __align__(16) ushort_t lds[65536];   // 128 KiB

    const int t   = threadIdx.x;                    // 0..511
    const int bm0 = blockIdx.y * 256;
    const int j0  = blockIdx.x * 64;

    // ---- staging precompute ----
    // A chunks: thread t owns phys chunk idx t (row r0=t>>2) and t+512
    // (row r0+128); logical k-chunk c0 = (t&3)^((t>>3)&3) (source-permuted
    // swizzle; same c0 for both rows since 512>>3 ≡ 0 mod 4).
    const int r0 = t >> 2;
    const int c0 = (t & 3) ^ ((t >> 3) & 3);
    const int aIdx0 = (bm0 + r0) * 1024 + c0 * 8;           // f32 elements
    // B: virtual row v -> gate (v>>4)&3, j = j0 + (v>>6)*16 + (v&15)
    const int g0  = (r0 >> 4) & 3;
    const int jv0 = j0 + ((r0 >> 6) << 4) + (r0 & 15);
    const int boff0 = g0 * WB_ELEMS + jv0 * 1024 + c0 * 8;  // bf16 elements

    // ---- fragment read addressing ----
    const int lane = t & 63;
    const int wid  = t >> 6;
    const int wr = wid >> 2, wc = wid & 3;          // 2M x 4N waves
    const int lr = lane & 15, lk = lane >> 4;
    const int xk = lk ^ ((lr >> 1) & 3);            // bank swizzle
    const int a_rd = (wr * 512 + lr * 4 + xk) * 8;  // ushort offset in A half
    const int b_rd = (wc * 256 + lr * 4 + xk) * 8;  // ushort offset in B half

    short8 af[4], bfr[4];
    floatx4 a00, a01, a02, a03, a10, a11, a12, a13;  // A-staging regs (named: rule 20)
    floatx4 p10, p11, p12, p13, p20, p21, p22, p23;  // prologue-only temps
    floatx4 acc[8][4] = {};   // [row-frag][gate]

    // ---- prologue: issue A(0,0),A(0,1),A(1,0),A(1,1) + B(0,*),B(1,0);
    // full drain (robust to any VMEM issue-order permutation in this
    // single clobber-free window), convert/write the first three A-halves,
    // make them visible. A(1,1) stays in regs a10-a13 for tile 0's p0. ----
    ISSUE_A(a00,a01,a02,a03, 0, 0);
    ISSUE_A(p10,p11,p12,p13, 0, 1);
    ISSUE_A(p20,p21,p22,p23, 1, 0);
    STAGE_B(0, 0, 0); STAGE_B(0, 1, 0);
    ISSUE_A(a10,a11,a12,a13, 1, 1);
    STAGE_B(1, 0, 1);
    WAIT_VM(0);
    CVT_WRITE(a00,a01,a02,a03, 0, 0);   // A(0,0)
    CVT_WRITE(p10,p11,p12,p13, 0, 1);   // A(0,1)
    CVT_WRITE(p20,p21,p22,p23, 1, 0);   // A(1,0)
    LGKM0();
    BAR();

    // ---- main loop: tiles 0..29 steady; tail 30/31 peeled ----
    for (int T = 0; T < 30; T += 2) {
        KTILE_STEADY(T,     0);
        KTILE_STEADY(T + 1, 1);
    }

    // tile 30 (slot 0): stages only A(31,1) + B(31,1); drain at p3
    {
        af[0]=RD_A(0,0,0); bfr[0]=RD_B(0,0,0); af[1]=RD_A(0,0,1); bfr[1]=RD_B(0,0,1);
        af[2]=RD_A(0,0,2); bfr[2]=RD_B(0,0,2); af[3]=RD_A(0,0,3); bfr[3]=RD_B(0,0,3);
        BAR(); MFMA16(0);
        WAIT_VM(2);                       // only B(31,0) gll may stay in flight
        CVT_WRITE(a10,a11,a12,a13, 1, 1); // A(31,1)
        LGKM0(); BAR();
        af[0]=RD_A(0,0,4); af[1]=RD_A(0,0,5); af[2]=RD_A(0,0,6); af[3]=RD_A(0,0,7);
        STAGE_B(31, 1, 1);
        BAR(); MFMA16(4); BAR();
        af[0]=RD_A(0,1,0); bfr[0]=RD_B(0,1,0); af[1]=RD_A(0,1,1); bfr[1]=RD_B(0,1,1);
        af[2]=RD_A(0,1,2); bfr[2]=RD_B(0,1,2); af[3]=RD_A(0,1,3); bfr[3]=RD_B(0,1,3);
        BAR(); MFMA16(0); BAR();
        af[0]=RD_A(0,1,4); af[1]=RD_A(0,1,5); af[2]=RD_A(0,1,6); af[3]=RD_A(0,1,7);
        BAR(); MFMA16(4);
        WAIT_VM(0);                       // B(31,0), B(31,1) landed
        BAR();
    }
    // tile 31 (slot 1): plain compute, no staging
    {
        af[0]=RD_A(1,0,0); bfr[0]=RD_B(1,0,0); af[1]=RD_A(1,0,1); bfr[1]=RD_B(1,0,1);
        af[2]=RD_A(1,0,2); bfr[2]=RD_B(1,0,2); af[3]=RD_A(1,0,3); bfr[3]=RD_B(1,0,3);
        BAR(); MFMA16(0); BAR();
        af[0]=RD_A(1,0,4); af[1]=RD_A(1,0,5); af[2]=RD_A(1,0,6); af[3]=RD_A(1,0,7);
        BAR(); MFMA16(4); BAR();
        af[0]=RD_A(1,1,0); bfr[0]=RD_B(1,1,0); af[1]=RD_A(1,1,1); bfr[1]=RD_B(1,1,1);
        af[2]=RD_A(1,1,2); bfr[2]=RD_B(1,1,2); af[3]=RD_A(1,1,3); bfr[3]=RD_B(1,1,3);
        BAR(); MFMA16(0); BAR();
        af[0]=RD_A(1,1,4); af[1]=RD_A(1,1,5); af[2]=RD_A(1,1,6); af[3]=RD_A(1,1,7);
        BAR(); MFMA16(4); BAR();
    }

    // ---- epilogue: 4 gates live in acc[rf][0..3], same lane/reg ----
    const int j = j0 + wc * 16 + lr;
    const float bi = Bi[j], bff = Bf[j], bg = Bg[j], bo = Bo[j];

    #pragma unroll
    for (int rf = 0; rf < 8; ++rf) {
        #pragma unroll
        for (int reg = 0; reg < 4; ++reg) {
            const int m = bm0 + wr * 128 + rf * 16 + lk * 4 + reg;
            const float zi = acc[rf][0][reg] + bi;
            const float zf = acc[rf][1][reg] + bff;
            const float zg = acc[rf][2][reg] + bg;
            const float zo = acc[rf][3][reg] + bo;
            const float ig = sigmoid_(zi);
            const float fg = sigmoid_(zf);
            const float gg = tanh_(zg);
            const float og = sigmoid_(zo);
            const float cp = Cprev[(size_t)m * H_ + j];
            const float cn = fg * cp + ig * gg;
            const float hn = og * tanh_(cn);
            Out[(size_t)m * H_ + j] = hn;                             // h_next (f32)
            Out[(size_t)B_ * H_ + (size_t)m * H_ + j] = cn;           // c_next (f32)
        }
    }
}

extern "C" void kernel_launch(void* const* d_in, const int* in_sizes, int n_in,
                              void* d_out, int out_size, void* d_ws, size_t ws_size,
                              hipStream_t stream)
{
    (void)in_sizes; (void)n_in; (void)out_size; (void)ws_size;
    const float* X   = (const float*)d_in[0];
    const float* Hin = (const float*)d_in[1];
    const float* Cp  = (const float*)d_in[2];
    const float* Wfx = (const float*)d_in[3];
    const float* Bf  = (const float*)d_in[4];
    const float* Wfh = (const float*)d_in[5];
    const float* Wix = (const float*)d_in[6];
    const float* Bi  = (const float*)d_in[7];
    const float* Wih = (const float*)d_in[8];
    const float* Wgx = (const float*)d_in[9];
    const float* Bg  = (const float*)d_in[10];
    const float* Wgh = (const float*)d_in[11];
    const float* Wox = (const float*)d_in[12];
    const float* Bo  = (const float*)d_in[13];
    const float* Woh = (const float*)d_in[14];
    float* Out = (float*)d_out;
    ushort_t* ws  = (ushort_t*)d_ws;

    // prep: f32 -> bf16 weights only (x/h cvt fused into GEMM A-staging)
    cvt_kernel<<<dim3(4096), dim3(256), 0, stream>>>(
        Wix, Wfx, Wgx, Wox, Wih, Wfh, Wgh, Woh, ws);

    dim3 grid(H_ / 64, B_ / 256);   // 16 x 32 = 512 blocks
    lstm_cell_kernel<<<grid, dim3(512), 0, stream>>>(
        X, Hin, ws, Cp, Bi, Bf, Bg, Bo, Out);
}

// Round 6
// 319.532 us; speedup vs baseline: 1.0730x; 1.0494x over previous
//
#include <hip/hip_runtime.h>
#include <stdint.h>

typedef unsigned short ushort_t;
typedef __attribute__((ext_vector_type(8))) short short8;
typedef __attribute__((ext_vector_type(4))) float floatx4;

#define B_   8192
#define IN_  1024
#define H_   1024

#define XB_ELEMS   (B_ * IN_)            // 8388608
#define WB_ELEMS   (H_ * IN_)            // 1048576
// ws layout (ushort elements): Xb[8M] | Hb[8M] | Wb[8][1M]  (slots: i,f,g,o x-wts then i,f,g,o h-wts)
#define WS_XB   0
#define WS_HB   XB_ELEMS
#define WS_WB   (2 * XB_ELEMS)

__device__ __forceinline__ ushort_t f2bf(float f) {
    union { float f; uint32_t i; } v; v.f = f;
    uint32_t r = (v.i + 0x7fffu + ((v.i >> 16) & 1u)) >> 16;
    return (ushort_t)r;
}
__device__ __forceinline__ float sigmoid_(float x) {
    return 1.0f / (1.0f + __expf(-x));
}
__device__ __forceinline__ float tanh_(float x) {
    float xc = fminf(fmaxf(x, -20.f), 20.f);
    float e = __expf(2.f * xc);
    return (e - 1.f) / (e + 1.f);
}

// async global->LDS DMA, 16B/lane; dest must be wave-uniform base + lane*16.
__device__ __forceinline__ void gll16(const ushort_t* gsrc, ushort_t* ldst) {
    __builtin_amdgcn_global_load_lds(
        (const __attribute__((address_space(1))) void*)gsrc,
        (__attribute__((address_space(3))) void*)ldst,
        16, 0, 0);
}

// ---- prep: f32 -> bf16 for x, h, 8 weight matrices into ws (round-2 form;
// the fused-A experiment of rounds 3-5 was net-negative and is reverted) ----
__global__ __launch_bounds__(256) void cvt_kernel(
    const float* __restrict__ X,   const float* __restrict__ Hin,
    const float* __restrict__ Wix, const float* __restrict__ Wfx,
    const float* __restrict__ Wgx, const float* __restrict__ Wox,
    const float* __restrict__ Wih, const float* __restrict__ Wfh,
    const float* __restrict__ Wgh, const float* __restrict__ Woh,
    ushort_t* __restrict__ ws)
{
    const int c = blockIdx.x * 256 + threadIdx.x;
    const float* src;
    ushort_t* dst;
    int off;
    if (c < 2097152) {
        const int t = c >> 20;                 // 0 = x, 1 = h
        src = t ? Hin : X;
        dst = ws + (t ? WS_HB : WS_XB);
        off = (c & 1048575) * 8;
    } else {
        const int cc = c - 2097152;
        const int s = cc >> 17;                // weight slot 0..7
        const float* w =
            s == 0 ? Wix : s == 1 ? Wfx : s == 2 ? Wgx : s == 3 ? Wox :
            s == 4 ? Wih : s == 5 ? Wfh : s == 6 ? Wgh : Woh;
        src = w;
        dst = ws + WS_WB + s * WB_ELEMS;
        off = (cc & 131071) * 8;
    }
    float4 f0 = *(const float4*)(src + off);
    float4 f1 = *(const float4*)(src + off + 4);
    short8 o;
    o[0] = (short)f2bf(f0.x); o[1] = (short)f2bf(f0.y);
    o[2] = (short)f2bf(f0.z); o[3] = (short)f2bf(f0.w);
    o[4] = (short)f2bf(f1.x); o[5] = (short)f2bf(f1.y);
    o[6] = (short)f2bf(f1.z); o[7] = (short)f2bf(f1.w);
    *(short8*)(dst + off) = o;
}

// ============================================================================
// 256x256 tile, BK=64, 8 waves (2Mx4N).  ROUND-6: pipelined fragment reads.
//
// Round-2's counters showed per-K-tile time 5690 cyc = LDS-read service
// (2304 cyc/CU) + MFMA (2480 cyc/CU) SERIALIZED by the phase structure
// (reads in read-only windows, MFMA in MFMA-only windows; MfmaUtil 40.5%).
// This version issues every phase's ds_reads ONE PHASE EARLY (ping-pong
// frag regs afA/afB, bA/bB) so LDS service rides under the previous MFMA
// cluster, and collapses to ONE barrier per phase (4/tile).
//
// Steady K-tile T (slot S = T&1), phases = [BAR; stage; prefetch-reads; MFMA]:
//   p0: stage A(T+1,kh1)->S^1 | read A(S,kh0,rf4-7)->afB, B(S,kh1,0-1)->bB | MFMA(afA,bA,rf0-3)
//   p1: stage B(T+1,kh1)->S^1 | read A(S,kh1,rf0-3)->afA, B(S,kh1,2-3)->bB | MFMA(afB,bA,rf4-7)
//   p2: stage A(T+2,kh0)->S   | read A(S,kh1,rf4-7)->afB                   | MFMA(afA,bB,rf0-3); vmcnt(2)
//   p3: stage B(T+2,kh0)->S   | read A(S^1,kh0,rf0-3)->afA, B(S^1,kh0)->bA | MFMA(afB,bB,rf4-7)
//
// vmcnt(2) at p2-end (per-wave FIFO: since T-1's vmcnt the stream is
// [T-1p3 B][Tp0 A][Tp1 B][Tp2 A], keep newest 2 = Tp2's own A-gll pair):
// drains ALL FOUR staged halves of tile T+1 -> after p3's barrier the whole
// next slot is visible, so p3 may prefetch its p0 fragments.  Never 0 in
// the steady loop.  Tightest wait: Tp1's B-gll (1 phase old) -- B weights
// are L2-resident after warmup (2 MB/XCD working set).
//
// WAR safety with 1 barrier/phase: each stage overwrites a region whose
// last reads are consumed by an MFMA that precedes the stage's opening
// barrier in every wave's program order (checked for all 4 stages).
//
// LDS (128 KiB): slot s: A at s*32768 + kh*8192 (ushort), B at +16384.
// Chunk swizzle (source-permuted, DMA dest linear): logical (row r, chunk
// c) at phys idx r*4 + (c ^ ((r>>1)&3)) -> conflict-free frag reads
// (SQ_LDS_BANK_CONFLICT == 0 measured).  Virtual B row v: gate=(v>>4)&3,
// j=j0+(v>>6)*16+(v&15).  K order: X tiles 0-15 then H 16-31 (numerics
// identical to round 2, absmax 0.015625).
// ============================================================================

#define BAR()  __builtin_amdgcn_s_barrier()
#define WAIT_VM(N) asm volatile("s_waitcnt vmcnt(" #N ")" ::: "memory")

#define STAGE_A(TS, KH, DS) do{ \
    const ushort_t* _s = (((TS) < 16) ? Xb : Hb) + (((TS) & 15) * 64 + (KH) * 32); \
    ushort_t* _d = lds + ((DS) * 32768 + (KH) * 8192); \
    gll16(_s + aoff0,          _d + t * 8); \
    gll16(_s + aoff0 + 131072, _d + 4096 + t * 8); \
  }while(0)

#define STAGE_B(TS, KH, DS) do{ \
    const ushort_t* _s = Wb + ((((TS) < 16) ? 0 : 4 * WB_ELEMS) + (((TS) & 15) * 64 + (KH) * 32)); \
    ushort_t* _d = lds + ((DS) * 32768 + 16384 + (KH) * 8192); \
    gll16(_s + boff0,         _d + t * 8); \
    gll16(_s + boff0 + 32768, _d + 4096 + t * 8); \
  }while(0)

#define RD_A(S, KH, RF) (*(const short8*)(lds + ((S) * 32768 + (KH) * 8192) + a_rd + (RF) * 512))
#define RD_B(S, KH, CT) (*(const short8*)(lds + ((S) * 32768 + 16384 + (KH) * 8192) + b_rd + (CT) * 512))

#define MFMA16(AF, BF, RFB) do{ \
    __builtin_amdgcn_s_setprio(1); \
    _Pragma("unroll") \
    for (int _rf = 0; _rf < 4; ++_rf) \
      _Pragma("unroll") \
      for (int _ct = 0; _ct < 4; ++_ct) \
        acc[(RFB) + _rf][_ct] = __builtin_amdgcn_mfma_f32_16x16x32_bf16( \
            AF[_rf], BF[_ct], acc[(RFB) + _rf][_ct], 0, 0, 0); \
    __builtin_amdgcn_s_setprio(0); \
  }while(0)

#define KTILE(T, S, ST01, ST23, PRE, VMQ) do{ \
    /* p0 */ \
    BAR(); \
    if (ST01) STAGE_A((T) + 1, 1, (S) ^ 1); \
    afB[0]=RD_A(S,0,4); afB[1]=RD_A(S,0,5); afB[2]=RD_A(S,0,6); afB[3]=RD_A(S,0,7); \
    bB[0]=RD_B(S,1,0);  bB[1]=RD_B(S,1,1); \
    MFMA16(afA, bA, 0); \
    /* p1 */ \
    BAR(); \
    if (ST01) STAGE_B((T) + 1, 1, (S) ^ 1); \
    afA[0]=RD_A(S,1,0); afA[1]=RD_A(S,1,1); afA[2]=RD_A(S,1,2); afA[3]=RD_A(S,1,3); \
    bB[2]=RD_B(S,1,2);  bB[3]=RD_B(S,1,3); \
    MFMA16(afB, bA, 4); \
    /* p2 */ \
    BAR(); \
    if (ST23) STAGE_A((T) + 2, 0, S); \
    afB[0]=RD_A(S,1,4); afB[1]=RD_A(S,1,5); afB[2]=RD_A(S,1,6); afB[3]=RD_A(S,1,7); \
    MFMA16(afA, bB, 0); \
    VMQ; \
    /* p3 */ \
    BAR(); \
    if (ST23) STAGE_B((T) + 2, 0, S); \
    if (PRE) { \
      afA[0]=RD_A((S)^1,0,0); bA[0]=RD_B((S)^1,0,0); \
      afA[1]=RD_A((S)^1,0,1); bA[1]=RD_B((S)^1,0,1); \
      afA[2]=RD_A((S)^1,0,2); bA[2]=RD_B((S)^1,0,2); \
      afA[3]=RD_A((S)^1,0,3); bA[3]=RD_B((S)^1,0,3); \
    } \
    MFMA16(afB, bB, 4); \
}while(0)

__global__ __launch_bounds__(512, 2) void lstm_cell_kernel(
    const ushort_t* __restrict__ Xb,  const ushort_t* __restrict__ Hb,
    const ushort_t* __restrict__ Wb,  // 8 slots of [H][K] bf16
    const float* __restrict__ Cprev,
    const float* __restrict__ Bi, const float* __restrict__ Bf,
    const float* __restrict__ Bg, const float* __restrict__ Bo,
    float* __restrict__ Out)
{
    __shared__ __align__(16) ushort_t lds[65536];   // 128 KiB

    const int t   = threadIdx.x;                    // 0..511
    const int bm0 = blockIdx.y * 256;
    const int j0  = blockIdx.x * 64;

    // ---- staging precompute: thread t owns phys chunk idx t (row r0=t>>2)
    // and t+512 (row r0+128); logical k-chunk c0 = (t&3)^((t>>3)&3). ----
    const int r0 = t >> 2;
    const int c0 = (t & 3) ^ ((t >> 3) & 3);
    const int aoff0 = (bm0 + r0) * 1024 + c0 * 8;           // bf16 elements
    const int g0  = (r0 >> 4) & 3;
    const int jv0 = j0 + ((r0 >> 6) << 4) + (r0 & 15);
    const int boff0 = g0 * WB_ELEMS + jv0 * 1024 + c0 * 8;

    // ---- fragment read addressing ----
    const int lane = t & 63;
    const int wid  = t >> 6;
    const int wr = wid >> 2, wc = wid & 3;          // 2M x 4N waves
    const int lr = lane & 15, lk = lane >> 4;
    const int xk = lk ^ ((lr >> 1) & 3);            // bank swizzle
    const int a_rd = (wr * 512 + lr * 4 + xk) * 8;  // ushort offset in A half
    const int b_rd = (wc * 256 + lr * 4 + xk) * 8;  // ushort offset in B half

    short8 afA[4], afB[4], bA[4], bB[4];            // ping-pong frag regs
    floatx4 acc[8][4] = {};   // [row-frag][gate]

    // ---- prologue: stage tile 0 fully + tile 1 kh0; drain; prefetch
    // tile-0 p0 fragments (visible: drained before the barrier). ----
    STAGE_A(0, 0, 0); STAGE_B(0, 0, 0);
    STAGE_A(0, 1, 0); STAGE_B(0, 1, 0);
    STAGE_A(1, 0, 1); STAGE_B(1, 0, 1);
    WAIT_VM(0);
    BAR();
    afA[0]=RD_A(0,0,0); bA[0]=RD_B(0,0,0);
    afA[1]=RD_A(0,0,1); bA[1]=RD_B(0,0,1);
    afA[2]=RD_A(0,0,2); bA[2]=RD_B(0,0,2);
    afA[3]=RD_A(0,0,3); bA[3]=RD_B(0,0,3);

    // ---- main loop: tiles 0..29 steady; tail 30 (partial stage), 31 ----
    for (int T = 0; T < 30; T += 2) {
        KTILE(T,     0, 1, 1, 1, WAIT_VM(2));
        KTILE(T + 1, 1, 1, 1, 1, WAIT_VM(2));
    }
    KTILE(30, 0, 1, 0, 1, WAIT_VM(0));   // stages only tile 31's kh1; drain
    KTILE(31, 1, 0, 0, 0, (void)0);      // pure compute

    // ---- epilogue: 4 gates live in acc[rf][0..3], same lane/reg ----
    const int j = j0 + wc * 16 + lr;
    const float bi = Bi[j], bff = Bf[j], bg = Bg[j], bo = Bo[j];

    #pragma unroll
    for (int rf = 0; rf < 8; ++rf) {
        #pragma unroll
        for (int reg = 0; reg < 4; ++reg) {
            const int m = bm0 + wr * 128 + rf * 16 + lk * 4 + reg;
            const float zi = acc[rf][0][reg] + bi;
            const float zf = acc[rf][1][reg] + bff;
            const float zg = acc[rf][2][reg] + bg;
            const float zo = acc[rf][3][reg] + bo;
            const float ig = sigmoid_(zi);
            const float fg = sigmoid_(zf);
            const float gg = tanh_(zg);
            const float og = sigmoid_(zo);
            const float cp = Cprev[(size_t)m * H_ + j];
            const float cn = fg * cp + ig * gg;
            const float hn = og * tanh_(cn);
            Out[(size_t)m * H_ + j] = hn;                             // h_next (f32)
            Out[(size_t)B_ * H_ + (size_t)m * H_ + j] = cn;           // c_next (f32)
        }
    }
}

extern "C" void kernel_launch(void* const* d_in, const int* in_sizes, int n_in,
                              void* d_out, int out_size, void* d_ws, size_t ws_size,
                              hipStream_t stream)
{
    (void)in_sizes; (void)n_in; (void)out_size; (void)ws_size;
    const float* X   = (const float*)d_in[0];
    const float* Hin = (const float*)d_in[1];
    const float* Cp  = (const float*)d_in[2];
    const float* Wfx = (const float*)d_in[3];
    const float* Bf  = (const float*)d_in[4];
    const float* Wfh = (const float*)d_in[5];
    const float* Wix = (const float*)d_in[6];
    const float* Bi  = (const float*)d_in[7];
    const float* Wih = (const float*)d_in[8];
    const float* Wgx = (const float*)d_in[9];
    const float* Bg  = (const float*)d_in[10];
    const float* Wgh = (const float*)d_in[11];
    const float* Wox = (const float*)d_in[12];
    const float* Bo  = (const float*)d_in[13];
    const float* Woh = (const float*)d_in[14];
    float* Out = (float*)d_out;
    ushort_t* ws  = (ushort_t*)d_ws;

    // prep: f32 -> bf16 (x, h, 8 weights) into ws
    cvt_kernel<<<dim3(12288), dim3(256), 0, stream>>>(
        X, Hin, Wix, Wfx, Wgx, Wox, Wih, Wfh, Wgh, Woh, ws);

    dim3 grid(H_ / 64, B_ / 256);   // 16 x 32 = 512 blocks
    lstm_cell_kernel<<<grid, dim3(512), 0, stream>>>(
        ws + WS_XB, ws + WS_HB, ws + WS_WB,
        Cp, Bi, Bf, Bg, Bo, Out);
}